// Round 1
// baseline (1255.573 us; speedup 1.0000x reference)
//
#include <hip/hip_runtime.h>

#define Bn 4096
#define Tn 100
#define Dn 64
#define Hn 128

typedef _Float16 half8v __attribute__((ext_vector_type(8)));
typedef _Float16 half4v __attribute__((ext_vector_type(4)));
typedef float    float4v __attribute__((ext_vector_type(4)));

__device__ __forceinline__ float fast_tanh(float x) {
    float e = __expf(x + x);
    return 1.0f - 2.0f * __builtin_amdgcn_rcpf(e + 1.0f);
}
__device__ __forceinline__ float fast_sig(float x) {
    return __builtin_amdgcn_rcpf(1.0f + __expf(-x));
}

// Load an MFMA A-operand fragment of a stationary weight matrix W [nrows x ld],
// element j of lane l = W[n][k_base + j]  (8 consecutive k, fp32 -> fp16).
__device__ __forceinline__ half8v load_wfrag(const float* __restrict__ W, int ld, int n, int k) {
    const float* p = W + (size_t)n * ld + k;
    float4v a = *(const float4v*)p;
    float4v b = *(const float4v*)(p + 4);
    half8v r;
    r[0] = (_Float16)a[0]; r[1] = (_Float16)a[1]; r[2] = (_Float16)a[2]; r[3] = (_Float16)a[3];
    r[4] = (_Float16)b[0]; r[5] = (_Float16)b[1]; r[6] = (_Float16)b[2]; r[7] = (_Float16)b[3];
    return r;
}

// Persistent ODE-RNN kernel. 256 blocks x 256 threads (4 waves).
// Block owns 16 batch rows for all T steps.
// Transposed MFMA formulation: D'[n][m] = sum_k W[n][k] * v[m][k]
//   A-frag = weights (registers, lane: n = 16*ct + (l&15), k = 32*kt + (l>>4)*8 + j)
//   B-frag = activations vT (LDS row-major [16][136] f16, lane: m=l&15, 8 contiguous k)
//   D: lane holds 4 consecutive n (rows (l>>4)*4+r) at col m=l&15 -> contiguous b64/b128 writes.
__global__ __launch_bounds__(256, 1) void odernn_kernel(
    const float* __restrict__ x_seq, const float* __restrict__ t_seq,
    const float* __restrict__ W1,   const float* __restrict__ b1,
    const float* __restrict__ W2,   const float* __restrict__ b2,
    const float* __restrict__ W_ih, const float* __restrict__ W_hh,
    const float* __restrict__ b_ih, const float* __restrict__ b_hh,
    const float* __restrict__ W_mu, const float* __restrict__ b_mu,
    const float* __restrict__ W_lv, const float* __restrict__ b_lv,
    float* __restrict__ out)
{
    __shared__ _Float16 vbuf[16 * 136];   // v / h staging (fp16, B-operand layout), +8 pad
    __shared__ _Float16 abuf[16 * 136];   // tanh(u) staging
    __shared__ _Float16 xbuf[16 * 72];    // x_t staging (K=64), +8 pad
    __shared__ float    gibuf[16 * 388];  // gi = x Wih^T + bih   [m][3H], +4 pad
    __shared__ float    ghbuf[16 * 388];  // gh = h Whh^T + bhh
    __shared__ float    bih_l[384];
    __shared__ float    bhh_l[384];
    __shared__ float    ts_l[Tn];

    const int tid  = threadIdx.x;
    const int lane = tid & 63;
    const int w    = tid >> 6;        // wave 0..3
    const int q    = lane >> 4;       // quad 0..3
    const int m    = lane & 15;       // batch row within block (MFMA B/D col)
    const int blk  = blockIdx.x;

    // ---- init LDS ----
    for (int i = tid; i < 384; i += 256) { bih_l[i] = b_ih[i]; bhh_l[i] = b_hh[i]; }
    if (tid < Tn) ts_l[tid] = t_seq[tid];     // shared timestamps = first row of t_seq
    for (int i = tid; i < 16 * 136; i += 256) vbuf[i] = (_Float16)0.f;  // h0 = 0

    // ---- preload stationary weight fragments into registers ----
    half8v w1f[2][4], w2f[2][4], whhf[6][4], wihf[6][2];
#pragma unroll
    for (int c = 0; c < 2; c++) {
        int n = 16 * (2 * w + c) + m;
#pragma unroll
        for (int kt = 0; kt < 4; kt++) {
            int k = 32 * kt + q * 8;
            w1f[c][kt] = load_wfrag(W1, Hn, n, k);
            w2f[c][kt] = load_wfrag(W2, Hn, n, k);
        }
    }
#pragma unroll
    for (int cc = 0; cc < 6; cc++) {
        int n = 16 * (6 * w + cc) + m;
#pragma unroll
        for (int kt = 0; kt < 4; kt++) whhf[cc][kt] = load_wfrag(W_hh, Hn, n, 32 * kt + q * 8);
#pragma unroll
        for (int kt = 0; kt < 2; kt++) wihf[cc][kt] = load_wfrag(W_ih, Dn, n, 32 * kt + q * 8);
    }
    // biases for the f-GEMMs, kept in registers (4 consecutive n per lane)
    float4v b1q[2], b2q[2];
#pragma unroll
    for (int c = 0; c < 2; c++) {
        int n = 16 * (2 * w + c) + q * 4;
        b1q[c] = *(const float4v*)(b1 + n);
        b2q[c] = *(const float4v*)(b2 + n);
    }

    // hidden state in registers: h[c][r] lives at n = 16*(2w+c)+q*4+r, batch row m
    float4v h[2];
    {
        float4v zz = {0.f, 0.f, 0.f, 0.f};
        h[0] = zz; h[1] = zz;
    }

    // x prefetch: thread loads 4 contiguous d for its row
    const int mrow = tid >> 4;            // 0..15
    const int d4   = (tid & 15) * 4;      // 0..60
    const float* xptr = x_seq + ((size_t)(blk * 16 + mrow)) * (Tn * Dn) + d4;
    float4v xreg = *(const float4v*)(xptr);   // t = 0

    // f(v): u = v W1^T + b1 ; a = tanh(u) ; k = a W2^T + b2   (kk = C-layout result)
    auto feval = [&](float4v* kk) {
        float4v u[2];
#pragma unroll
        for (int c = 0; c < 2; c++) u[c] = b1q[c];
#pragma unroll
        for (int kt = 0; kt < 4; kt++) {
            half8v bf = *(const half8v*)(vbuf + m * 136 + kt * 32 + q * 8);
#pragma unroll
            for (int c = 0; c < 2; c++)
                u[c] = __builtin_amdgcn_mfma_f32_16x16x32_f16(w1f[c][kt], bf, u[c], 0, 0, 0);
        }
#pragma unroll
        for (int c = 0; c < 2; c++) {
            half4v pk;
#pragma unroll
            for (int r = 0; r < 4; r++) pk[r] = (_Float16)fast_tanh(u[c][r]);
            *(half4v*)(abuf + m * 136 + 16 * (2 * w + c) + q * 4) = pk;
        }
        __syncthreads();
#pragma unroll
        for (int c = 0; c < 2; c++) kk[c] = b2q[c];
#pragma unroll
        for (int kt = 0; kt < 4; kt++) {
            half8v af = *(const half8v*)(abuf + m * 136 + kt * 32 + q * 8);
#pragma unroll
            for (int c = 0; c < 2; c++)
                kk[c] = __builtin_amdgcn_mfma_f32_16x16x32_f16(w2f[c][kt], af, kk[c], 0, 0, 0);
        }
    };
    // stage v = h + alpha*k into vbuf (fp16)
    auto write_v = [&](float alpha, const float4v* kk) {
#pragma unroll
        for (int c = 0; c < 2; c++) {
            half4v pk;
#pragma unroll
            for (int r = 0; r < 4; r++) pk[r] = (_Float16)(h[c][r] + alpha * kk[c][r]);
            *(half4v*)(vbuf + m * 136 + 16 * (2 * w + c) + q * 4) = pk;
        }
    };

    __syncthreads();

#pragma unroll 1
    for (int t = 0; t < Tn; ++t) {
        // ---- stage x_t (fp16, B-operand layout) ----
        {
            half4v xp;
            xp[0] = (_Float16)xreg[0]; xp[1] = (_Float16)xreg[1];
            xp[2] = (_Float16)xreg[2]; xp[3] = (_Float16)xreg[3];
            *(half4v*)(xbuf + mrow * 72 + d4) = xp;
        }
        float tc    = ts_l[t];
        float tp    = (t > 0) ? ts_l[t - 1] : tc;
        float sub   = (tc - tp) * 0.25f;      // dt / N_RK4  (0 at t=0)
        float hsub  = 0.5f * sub;
        float sixth = sub * (1.0f / 6.0f);
        __syncthreads();
        if (t + 1 < Tn) xreg = *(const float4v*)(xptr + (t + 1) * Dn);  // prefetch

        // ---- gi = x Wih^T + bih  -> gibuf (read back at GRU; barriers in between) ----
        {
            float4v g[6];
#pragma unroll
            for (int cc = 0; cc < 6; cc++)
                g[cc] = *(const float4v*)(bih_l + 16 * (6 * w + cc) + q * 4);
#pragma unroll
            for (int kt = 0; kt < 2; kt++) {
                half8v bf = *(const half8v*)(xbuf + m * 72 + kt * 32 + q * 8);
#pragma unroll
                for (int cc = 0; cc < 6; cc++)
                    g[cc] = __builtin_amdgcn_mfma_f32_16x16x32_f16(wihf[cc][kt], bf, g[cc], 0, 0, 0);
            }
#pragma unroll
            for (int cc = 0; cc < 6; cc++)
                *(float4v*)(gibuf + m * 388 + 16 * (6 * w + cc) + q * 4) = g[cc];
        }

        // ---- RK4: 4 substeps (vbuf currently holds h) ----
        float4v k1[2], k2[2], k3[2], k4[2];
#pragma unroll 1
        for (int s = 0; s < 4; s++) {
            feval(k1);
            write_v(hsub, k1); __syncthreads();
            feval(k2);
            write_v(hsub, k2); __syncthreads();
            feval(k3);
            write_v(sub, k3);  __syncthreads();
            feval(k4);
#pragma unroll
            for (int c = 0; c < 2; c++) {
#pragma unroll
                for (int r = 0; r < 4; r++)
                    h[c][r] += sixth * (k1[c][r] + 2.0f * (k2[c][r] + k3[c][r]) + k4[c][r]);
            }
            // stage updated h
#pragma unroll
            for (int c = 0; c < 2; c++) {
                half4v pk;
#pragma unroll
                for (int r = 0; r < 4; r++) pk[r] = (_Float16)h[c][r];
                *(half4v*)(vbuf + m * 136 + 16 * (2 * w + c) + q * 4) = pk;
            }
            __syncthreads();
        }

        // ---- gh = h Whh^T + bhh ----
        {
            float4v g[6];
#pragma unroll
            for (int cc = 0; cc < 6; cc++)
                g[cc] = *(const float4v*)(bhh_l + 16 * (6 * w + cc) + q * 4);
#pragma unroll
            for (int kt = 0; kt < 4; kt++) {
                half8v bf = *(const half8v*)(vbuf + m * 136 + kt * 32 + q * 8);
#pragma unroll
                for (int cc = 0; cc < 6; cc++)
                    g[cc] = __builtin_amdgcn_mfma_f32_16x16x32_f16(whhf[cc][kt], bf, g[cc], 0, 0, 0);
            }
#pragma unroll
            for (int cc = 0; cc < 6; cc++)
                *(float4v*)(ghbuf + m * 388 + 16 * (6 * w + cc) + q * 4) = g[cc];
        }
        __syncthreads();

        // ---- GRU elementwise update for this wave's n-slice ----
#pragma unroll
        for (int c = 0; c < 2; c++) {
            int nb = 16 * (2 * w + c) + q * 4;
            const float* gi0 = gibuf + m * 388;
            const float* gh0 = ghbuf + m * 388;
            float4v gir = *(const float4v*)(gi0 + nb);
            float4v giz = *(const float4v*)(gi0 + 128 + nb);
            float4v gin = *(const float4v*)(gi0 + 256 + nb);
            float4v ghr = *(const float4v*)(gh0 + nb);
            float4v ghz = *(const float4v*)(gh0 + 128 + nb);
            float4v ghn = *(const float4v*)(gh0 + 256 + nb);
            half4v pk;
#pragma unroll
            for (int r = 0; r < 4; r++) {
                float rr = fast_sig(gir[r] + ghr[r]);
                float zz = fast_sig(giz[r] + ghz[r]);
                float nn = fast_tanh(gin[r] + rr * ghn[r]);
                float hv = (1.0f - zz) * nn + zz * h[c][r];
                h[c][r] = hv;
                pk[r]   = (_Float16)hv;
            }
            *(half4v*)(vbuf + m * 136 + nb) = pk;  // safe: gh reads preceded the barrier above
        }
        // next-iteration barrier (after x staging) publishes vbuf
    }

    __syncthreads();  // publish final h

    // ---- epilogue: mu = h Wmu^T + bmu ; logvar = h Wlv^T + blv ----
#pragma unroll
    for (int mat = 0; mat < 2; mat++) {
        const float* Wm = mat ? W_lv : W_mu;
        const float* bm = mat ? b_lv : b_mu;
        float4v acc[2];
#pragma unroll
        for (int c = 0; c < 2; c++)
            acc[c] = *(const float4v*)(bm + 16 * (2 * w + c) + q * 4);
#pragma unroll
        for (int kt = 0; kt < 4; kt++) {
            half8v bf = *(const half8v*)(vbuf + m * 136 + kt * 32 + q * 8);
#pragma unroll
            for (int c = 0; c < 2; c++) {
                half8v af = load_wfrag(Wm, Hn, 16 * (2 * w + c) + m, 32 * kt + q * 8);
                acc[c] = __builtin_amdgcn_mfma_f32_16x16x32_f16(af, bf, acc[c], 0, 0, 0);
            }
        }
#pragma unroll
        for (int c = 0; c < 2; c++) {
            int n = 16 * (2 * w + c) + q * 4;
            *(float4v*)(out + (size_t)mat * Bn * Hn + (size_t)(blk * 16 + m) * Hn + n) = acc[c];
        }
    }
}

extern "C" void kernel_launch(void* const* d_in, const int* in_sizes, int n_in,
                              void* d_out, int out_size, void* d_ws, size_t ws_size,
                              hipStream_t stream) {
    (void)in_sizes; (void)n_in; (void)d_ws; (void)ws_size; (void)out_size;
    odernn_kernel<<<dim3(Bn / 16), dim3(256), 0, stream>>>(
        (const float*)d_in[0],  (const float*)d_in[1],  (const float*)d_in[2],
        (const float*)d_in[3],  (const float*)d_in[4],  (const float*)d_in[5],
        (const float*)d_in[6],  (const float*)d_in[7],  (const float*)d_in[8],
        (const float*)d_in[9],  (const float*)d_in[10], (const float*)d_in[11],
        (const float*)d_in[12], (const float*)d_in[13], (float*)d_out);
}

// Round 2
// 967.184 us; speedup vs baseline: 1.2982x; 1.2982x over previous
//
#include <hip/hip_runtime.h>

#define Bn 4096
#define Tn 100
#define Dn 64
#define Hn 128

typedef _Float16 half8v __attribute__((ext_vector_type(8)));
typedef _Float16 half4v __attribute__((ext_vector_type(4)));
typedef float    float4v __attribute__((ext_vector_type(4)));
typedef float    float2v __attribute__((ext_vector_type(2)));

__device__ __forceinline__ float fast_tanh(float x) {
    float e = __expf(x + x);
    return 1.0f - 2.0f * __builtin_amdgcn_rcpf(e + 1.0f);
}
__device__ __forceinline__ float fast_sig(float x) {
    return __builtin_amdgcn_rcpf(1.0f + __expf(-x));
}

// A-operand fragment of stationary weight W [n x ld]: lane gets W[n][k..k+7] fp32->fp16.
__device__ __forceinline__ half8v load_wfrag(const float* __restrict__ W, int ld, int n, int k) {
    const float* p = W + (size_t)n * ld + k;
    float4v a = *(const float4v*)p;
    float4v b = *(const float4v*)(p + 4);
    half8v r;
    r[0] = (_Float16)a[0]; r[1] = (_Float16)a[1]; r[2] = (_Float16)a[2]; r[3] = (_Float16)a[3];
    r[4] = (_Float16)b[0]; r[5] = (_Float16)b[1]; r[6] = (_Float16)b[2]; r[7] = (_Float16)b[3];
    return r;
}

// Persistent ODE-RNN kernel. 256 blocks x 512 threads (8 waves, 2 waves/SIMD).
// Block owns 16 batch rows for all T steps; n-dimension split across 8 waves.
// Transposed MFMA: D'[n][m] = sum_k W[n][k] * v[m][k]
//   A = weights in registers (lane: n = 16*tile + (l&15), k = 32*kt + (l>>4)*8 + j)
//   B = activations in LDS [16][136] f16 (lane: m = l&15, 8 contiguous k)
//   C/D: lane holds 4 consecutive n (rows q*4+r) for col m -> matches h register layout.
// GRU gates: wave w computes gate tiles {w, 8+w, 16+w} (r,z,n for n in [16w,16w+16))
// entirely in registers -- no LDS round-trip for gi/gh.
__global__ __launch_bounds__(512) void odernn_kernel(
    const float* __restrict__ x_seq, const float* __restrict__ t_seq,
    const float* __restrict__ W1,   const float* __restrict__ b1,
    const float* __restrict__ W2,   const float* __restrict__ b2,
    const float* __restrict__ W_ih, const float* __restrict__ W_hh,
    const float* __restrict__ b_ih, const float* __restrict__ b_hh,
    const float* __restrict__ W_mu, const float* __restrict__ b_mu,
    const float* __restrict__ W_lv, const float* __restrict__ b_lv,
    float* __restrict__ out)
{
    __shared__ _Float16 vbuf[16 * 136];   // v / h staging (fp16, B-layout), stride 136 (odd 16B-chunks)
    __shared__ _Float16 abuf[16 * 136];   // tanh(u) staging
    __shared__ _Float16 xbuf[16 * 72];    // x_t staging (K=64)
    __shared__ float    ts_l[Tn];

    const int tid  = threadIdx.x;
    const int lane = tid & 63;
    const int w    = tid >> 6;        // wave 0..7 = n-tile owner
    const int q    = lane >> 4;       // quad 0..3
    const int m    = lane & 15;       // batch row within block
    const int blk  = blockIdx.x;

    // ---- init LDS ----
    if (tid < Tn) ts_l[tid] = t_seq[tid];
    for (int i = tid; i < 16 * 136; i += 512) vbuf[i] = (_Float16)0.f;  // h0 = 0

    // ---- stationary weight fragments (per-wave n-tile) ----
    half8v w1f[4], w2f[4], whhf[3][4], wihf[3][2];
    {
        int n = 16 * w + m;
#pragma unroll
        for (int kt = 0; kt < 4; kt++) {
            w1f[kt] = load_wfrag(W1, Hn, n, 32 * kt + q * 8);
            w2f[kt] = load_wfrag(W2, Hn, n, 32 * kt + q * 8);
        }
    }
#pragma unroll
    for (int g = 0; g < 3; g++) {                 // g: 0=r gate, 1=z, 2=n
        int n = 128 * g + 16 * w + m;
#pragma unroll
        for (int kt = 0; kt < 4; kt++) whhf[g][kt] = load_wfrag(W_hh, Hn, n, 32 * kt + q * 8);
#pragma unroll
        for (int kt = 0; kt < 2; kt++) wihf[g][kt] = load_wfrag(W_ih, Dn, n, 32 * kt + q * 8);
    }
    float4v b1q = *(const float4v*)(b1 + 16 * w + q * 4);
    float4v b2q = *(const float4v*)(b2 + 16 * w + q * 4);
    float4v bihq[3], bhhq[3];
#pragma unroll
    for (int g = 0; g < 3; g++) {
        bihq[g] = *(const float4v*)(b_ih + 128 * g + 16 * w + q * 4);
        bhhq[g] = *(const float4v*)(b_hh + 128 * g + 16 * w + q * 4);
    }

    // hidden state: h[r] at n = 16*w + q*4 + r, batch col m  (MFMA C layout)
    float4v h = {0.f, 0.f, 0.f, 0.f};

    // x prefetch: 512 threads, thread loads 2 contiguous floats of its row
    const int xrow = tid >> 5;            // 0..15
    const int xcol = (tid & 31) * 2;      // 0..62
    const float* xptr = x_seq + (size_t)(blk * 16 + xrow) * (Tn * Dn) + xcol;
    float2v xreg = *(const float2v*)xptr;

    const _Float16* vb = vbuf + m * 136 + q * 8;
    const _Float16* ab = abuf + m * 136 + q * 8;

    // f(v): u = v W1^T + b1 ; a = tanh(u) ; kk = a W2^T + b2
    auto feval = [&](float4v& kk) {
        float4v u = b1q;
#pragma unroll
        for (int kt = 0; kt < 4; kt++)
            u = __builtin_amdgcn_mfma_f32_16x16x32_f16(w1f[kt], *(const half8v*)(vb + kt * 32), u, 0, 0, 0);
        half4v pk;
#pragma unroll
        for (int r = 0; r < 4; r++) pk[r] = (_Float16)fast_tanh(u[r]);
        *(half4v*)(abuf + m * 136 + 16 * w + q * 4) = pk;
        __syncthreads();
        kk = b2q;
#pragma unroll
        for (int kt = 0; kt < 4; kt++)
            kk = __builtin_amdgcn_mfma_f32_16x16x32_f16(w2f[kt], *(const half8v*)(ab + kt * 32), kk, 0, 0, 0);
    };
    auto write_v = [&](float alpha, const float4v& kk) {   // stage v = h + alpha*kk
        half4v pk;
#pragma unroll
        for (int r = 0; r < 4; r++) pk[r] = (_Float16)(h[r] + alpha * kk[r]);
        *(half4v*)(vbuf + m * 136 + 16 * w + q * 4) = pk;
    };

    __syncthreads();   // publish ts_l + h0 before first use

#pragma unroll 1
    for (int t = 0; t < Tn; ++t) {
        // ---- stage x_t ----
        {
            _Float16 x0 = (_Float16)xreg[0], x1 = (_Float16)xreg[1];
            _Float16* xp = xbuf + xrow * 72 + xcol;
            xp[0] = x0; xp[1] = x1;
        }
        float tc    = ts_l[t];
        float tp    = (t > 0) ? ts_l[t - 1] : tc;
        float sub   = (tc - tp) * 0.25f;      // dt / N_RK4 (0 at t=0)
        float hsub  = 0.5f * sub;
        float sixth = sub * (1.0f / 6.0f);
        float third = sub * (1.0f / 3.0f);
        __syncthreads();                      // publish xbuf (+ vbuf h from prev step)
        if (t + 1 < Tn) xreg = *(const float2v*)(xptr + (t + 1) * Dn);  // prefetch

        // ---- gi = x Wih^T + bih  (registers, lives across RK4) ----
        float4v gi[3];
#pragma unroll
        for (int g = 0; g < 3; g++) gi[g] = bihq[g];
#pragma unroll
        for (int kt = 0; kt < 2; kt++) {
            half8v bf = *(const half8v*)(xbuf + m * 72 + kt * 32 + q * 8);
#pragma unroll
            for (int g = 0; g < 3; g++)
                gi[g] = __builtin_amdgcn_mfma_f32_16x16x32_f16(wihf[g][kt], bf, gi[g], 0, 0, 0);
        }

        // ---- RK4: 4 substeps (vbuf holds current h) ----
#pragma unroll 1
        for (int s = 0; s < 4; s++) {
            float4v kk, acc;
            feval(kk);                                   // k1
#pragma unroll
            for (int r = 0; r < 4; r++) acc[r] = h[r] + sixth * kk[r];
            write_v(hsub, kk); __syncthreads();
            feval(kk);                                   // k2
#pragma unroll
            for (int r = 0; r < 4; r++) acc[r] += third * kk[r];
            write_v(hsub, kk); __syncthreads();
            feval(kk);                                   // k3
#pragma unroll
            for (int r = 0; r < 4; r++) acc[r] += third * kk[r];
            write_v(sub, kk); __syncthreads();
            feval(kk);                                   // k4
#pragma unroll
            for (int r = 0; r < 4; r++) h[r] = acc[r] + sixth * kk[r];
            {
                half4v pk;
#pragma unroll
                for (int r = 0; r < 4; r++) pk[r] = (_Float16)h[r];
                *(half4v*)(vbuf + m * 136 + 16 * w + q * 4) = pk;
            }
            __syncthreads();
        }

        // ---- gh = h Whh^T + bhh (registers) ----
        float4v gh[3];
#pragma unroll
        for (int g = 0; g < 3; g++) gh[g] = bhhq[g];
#pragma unroll
        for (int kt = 0; kt < 4; kt++) {
            half8v bf = *(const half8v*)(vb + kt * 32);
#pragma unroll
            for (int g = 0; g < 3; g++)
                gh[g] = __builtin_amdgcn_mfma_f32_16x16x32_f16(whhf[g][kt], bf, gh[g], 0, 0, 0);
        }
        __syncthreads();   // all waves done reading vbuf(h) before overwrite

        // ---- GRU update (pure registers; gate tiles align with h tile) ----
        {
            half4v pk;
#pragma unroll
            for (int r = 0; r < 4; r++) {
                float rr = fast_sig(gi[0][r] + gh[0][r]);
                float zz = fast_sig(gi[1][r] + gh[1][r]);
                float nn = fast_tanh(gi[2][r] + rr * gh[2][r]);
                float hv = (1.0f - zz) * nn + zz * h[r];
                h[r] = hv;
                pk[r] = (_Float16)hv;
            }
            *(half4v*)(vbuf + m * 136 + 16 * w + q * 4) = pk;
        }
        // next-iteration barrier (after x staging) publishes vbuf
    }

    __syncthreads();   // publish final h

    // ---- epilogue: mu = h Wmu^T + bmu ; logvar = h Wlv^T + blv ----
#pragma unroll
    for (int mat = 0; mat < 2; mat++) {
        const float* Wm = mat ? W_lv : W_mu;
        const float* bm = mat ? b_lv : b_mu;
        float4v acc = *(const float4v*)(bm + 16 * w + q * 4);
#pragma unroll
        for (int kt = 0; kt < 4; kt++) {
            half8v af = load_wfrag(Wm, Hn, 16 * w + m, 32 * kt + q * 8);
            acc = __builtin_amdgcn_mfma_f32_16x16x32_f16(af, *(const half8v*)(vb + kt * 32), acc, 0, 0, 0);
        }
        *(float4v*)(out + (size_t)mat * Bn * Hn + (size_t)(blk * 16 + m) * Hn + 16 * w + q * 4) = acc;
    }
}

extern "C" void kernel_launch(void* const* d_in, const int* in_sizes, int n_in,
                              void* d_out, int out_size, void* d_ws, size_t ws_size,
                              hipStream_t stream) {
    (void)in_sizes; (void)n_in; (void)d_ws; (void)ws_size; (void)out_size;
    odernn_kernel<<<dim3(Bn / 16), dim3(512), 0, stream>>>(
        (const float*)d_in[0],  (const float*)d_in[1],  (const float*)d_in[2],
        (const float*)d_in[3],  (const float*)d_in[4],  (const float*)d_in[5],
        (const float*)d_in[6],  (const float*)d_in[7],  (const float*)d_in[8],
        (const float*)d_in[9],  (const float*)d_in[10], (const float*)d_in[11],
        (const float*)d_in[12], (const float*)d_in[13], (float*)d_out);
}

// Round 3
// 811.200 us; speedup vs baseline: 1.5478x; 1.1923x over previous
//
#include <hip/hip_runtime.h>

#define Bn 4096
#define Tn 100
#define Dn 64
#define Hn 128

typedef _Float16 half8v __attribute__((ext_vector_type(8)));
typedef _Float16 half4v __attribute__((ext_vector_type(4)));
typedef float    float4v __attribute__((ext_vector_type(4)));
typedef float    float2v __attribute__((ext_vector_type(2)));

__device__ __forceinline__ float fast_tanh(float x) {
    float e = __expf(x + x);
    return 1.0f - 2.0f * __builtin_amdgcn_rcpf(e + 1.0f);
}
__device__ __forceinline__ float fast_sig(float x) {
    return __builtin_amdgcn_rcpf(1.0f + __expf(-x));
}
__device__ __forceinline__ float4v tanh4(float4v u) {
    float4v a;
#pragma unroll
    for (int r = 0; r < 4; r++) a[r] = fast_tanh(u[r]);
    return a;
}
__device__ __forceinline__ half4v pack4(float4v v) {
    half4v p;
#pragma unroll
    for (int r = 0; r < 4; r++) p[r] = (_Float16)v[r];
    return p;
}

// A-operand fragment of stationary weight W [n x ld]: lane gets W[n][k..k+7] fp32->fp16.
__device__ __forceinline__ half8v load_wfrag(const float* __restrict__ W, int ld, int n, int k) {
    const float* p = W + (size_t)n * ld + k;
    float4v a = *(const float4v*)p;
    float4v b = *(const float4v*)(p + 4);
    half8v r;
    r[0] = (_Float16)a[0]; r[1] = (_Float16)a[1]; r[2] = (_Float16)a[2]; r[3] = (_Float16)a[3];
    r[4] = (_Float16)b[0]; r[5] = (_Float16)b[1]; r[6] = (_Float16)b[2]; r[7] = (_Float16)b[3];
    return r;
}

// Persistent ODE-RNN kernel. 256 blocks x 512 threads (8 waves, 2 waves/SIMD).
// Block owns 16 batch rows; n-split over 8 waves; fused RK4 via M = W1*W2:
//   u_{i+1} = u_h + coef*(a_i M^T + c1),  u_h <- u_h + (sub/6) A M^T + sub*c1,
//   h <- h + (sub/6) (sum_s A_s) W2^T + 4 sub b2   (one W2-GEMM per step)
// => 4 exchange intervals per substep instead of 8.
__global__ __launch_bounds__(512) void odernn_kernel(
    const float* __restrict__ x_seq, const float* __restrict__ t_seq,
    const float* __restrict__ W1,   const float* __restrict__ b1,
    const float* __restrict__ W2,   const float* __restrict__ b2,
    const float* __restrict__ W_ih, const float* __restrict__ W_hh,
    const float* __restrict__ b_ih, const float* __restrict__ b_hh,
    const float* __restrict__ W_mu, const float* __restrict__ b_mu,
    const float* __restrict__ W_lv, const float* __restrict__ b_lv,
    float* __restrict__ out)
{
    __shared__ _Float16 vbuf[16 * 136];      // h exchange (fp16, [m][n] B-layout)
    __shared__ _Float16 abuf[2][16 * 136];   // a_i / A / Abar exchange, ping-pong
    __shared__ _Float16 xbuf[16 * 72];       // x_t staging
    __shared__ float    ts_l[Tn];
    __shared__ float    c1s[Hn];             // c1 = b2 @ W1^T

    const int tid  = threadIdx.x;
    const int lane = tid & 63;
    const int w    = tid >> 6;        // wave 0..7 = n-tile owner
    const int q    = lane >> 4;
    const int m    = lane & 15;
    const int blk  = blockIdx.x;

    if (tid < Tn) ts_l[tid] = t_seq[tid];
    for (int i = tid; i < 16 * 136; i += 512) vbuf[i] = (_Float16)0.f;  // h0 = 0
    if (tid < Hn) {                                   // c1[n] = dot(b2, W1[n][:])
        float acc = 0.f;
        const float* r1 = W1 + (size_t)tid * Hn;
#pragma unroll 4
        for (int j = 0; j < Hn; j++) acc += b2[j] * r1[j];
        c1s[tid] = acc;
    }

    // ---- stationary weight fragments ----
    const int n0 = 16 * w + m;
    half8v w1f[4], w2f[4], whhf[3][4], wihf[3][2];
#pragma unroll
    for (int kt = 0; kt < 4; kt++) {
        w1f[kt] = load_wfrag(W1, Hn, n0, 32 * kt + q * 8);
        w2f[kt] = load_wfrag(W2, Hn, n0, 32 * kt + q * 8);
    }
#pragma unroll
    for (int g = 0; g < 3; g++) {                 // 0=r, 1=z, 2=n gate
        int n = 128 * g + n0;
#pragma unroll
        for (int kt = 0; kt < 4; kt++) whhf[g][kt] = load_wfrag(W_hh, Hn, n, 32 * kt + q * 8);
#pragma unroll
        for (int kt = 0; kt < 2; kt++) wihf[g][kt] = load_wfrag(W_ih, Dn, n, 32 * kt + q * 8);
    }
    float4v b1q = *(const float4v*)(b1 + 16 * w + q * 4);
    float4v b2q = *(const float4v*)(b2 + 16 * w + q * 4);
    float4v bihq[3], bhhq[3];
#pragma unroll
    for (int g = 0; g < 3; g++) {
        bihq[g] = *(const float4v*)(b_ih + 128 * g + 16 * w + q * 4);
        bhhq[g] = *(const float4v*)(b_hh + 128 * g + 16 * w + q * 4);
    }

    // ---- M = W1 @ W2 fragments (one-time VALU dot; A-layout: M[n0][32kt+8q+j]) ----
    float4v accM[4][2];
#pragma unroll
    for (int kt = 0; kt < 4; kt++) {
        float4v zz = {0.f, 0.f, 0.f, 0.f};
        accM[kt][0] = zz; accM[kt][1] = zz;
    }
    {
        const float* w1row = W1 + (size_t)n0 * Hn;
        for (int j = 0; j < Hn; j++) {
            float w1v = w1row[j];
            const float* w2r = W2 + (size_t)j * Hn + q * 8;
#pragma unroll
            for (int kt = 0; kt < 4; kt++) {
                float4v aa = *(const float4v*)(w2r + 32 * kt);
                float4v bb = *(const float4v*)(w2r + 32 * kt + 4);
#pragma unroll
                for (int r = 0; r < 4; r++) {
                    accM[kt][0][r] += w1v * aa[r];
                    accM[kt][1][r] += w1v * bb[r];
                }
            }
        }
    }
    half8v w21f[4];
#pragma unroll
    for (int kt = 0; kt < 4; kt++) {
#pragma unroll
        for (int r = 0; r < 4; r++) {
            w21f[kt][r]     = (_Float16)accM[kt][0][r];
            w21f[kt][r + 4] = (_Float16)accM[kt][1][r];
        }
    }

    float4v h = {0.f, 0.f, 0.f, 0.f};   // C-layout: n = 16w+4q+r, col m

    // x prefetch
    const int xrow = tid >> 5;
    const int xcol = (tid & 31) * 2;
    const float* xptr = x_seq + (size_t)(blk * 16 + xrow) * (Tn * Dn) + xcol;
    float2v xreg = *(const float2v*)xptr;

    const int wslot = m * 136 + 16 * w + q * 4;   // C-layout store slot

    // K=128 GEMM, 2 independent MFMA chains of 2 (shorter dep chain)
    auto gemm4 = [&](const half8v* Wf, const _Float16* base, float4v cin) -> float4v {
        const _Float16* p = base + m * 136 + q * 8;
        half8v bf0 = *(const half8v*)(p);
        half8v bf1 = *(const half8v*)(p + 32);
        half8v bf2 = *(const half8v*)(p + 64);
        half8v bf3 = *(const half8v*)(p + 96);
        float4v o1 = cin;
        float4v o2 = {0.f, 0.f, 0.f, 0.f};
        o1 = __builtin_amdgcn_mfma_f32_16x16x32_f16(Wf[0], bf0, o1, 0, 0, 0);
        o2 = __builtin_amdgcn_mfma_f32_16x16x32_f16(Wf[2], bf2, o2, 0, 0, 0);
        o1 = __builtin_amdgcn_mfma_f32_16x16x32_f16(Wf[1], bf1, o1, 0, 0, 0);
        o2 = __builtin_amdgcn_mfma_f32_16x16x32_f16(Wf[3], bf3, o2, 0, 0, 0);
#pragma unroll
        for (int r = 0; r < 4; r++) o1[r] += o2[r];
        return o1;
    };

    float4v c1q;
    __syncthreads();     // publish ts_l, c1s, vbuf(h0)
#pragma unroll
    for (int r = 0; r < 4; r++) c1q[r] = c1s[16 * w + q * 4 + r];
    const float4v zero4 = {0.f, 0.f, 0.f, 0.f};

#pragma unroll 1
    for (int t = 0; t < Tn; ++t) {
        // ---- stage x_t ----
        {
            _Float16* xp = xbuf + xrow * 72 + xcol;
            xp[0] = (_Float16)xreg[0]; xp[1] = (_Float16)xreg[1];
        }
        float tc  = ts_l[t];
        float tp  = (t > 0) ? ts_l[t - 1] : tc;
        float sub = (tc - tp) * 0.25f;      // dt / N_RK4 (0 at t=0)
        float hs  = 0.5f * sub;
        float s6  = sub * (1.0f / 6.0f);
        __syncthreads();                    // publish xbuf + vbuf(h)
        if (t + 1 < Tn) xreg = *(const float2v*)(xptr + (t + 1) * Dn);

        // ---- interval A: gi = x Wih^T + bih  and  u_h = h W1^T + b1 ----
        float4v gi[3];
        {
            const _Float16* xp = xbuf + m * 72 + q * 8;
            half8v xf0 = *(const half8v*)(xp);
            half8v xf1 = *(const half8v*)(xp + 32);
#pragma unroll
            for (int g = 0; g < 3; g++) {
                float4v acc = bihq[g];
                acc = __builtin_amdgcn_mfma_f32_16x16x32_f16(wihf[g][0], xf0, acc, 0, 0, 0);
                acc = __builtin_amdgcn_mfma_f32_16x16x32_f16(wihf[g][1], xf1, acc, 0, 0, 0);
                gi[g] = acc;
            }
        }
        float4v u_h = gemm4(w1f, vbuf, b1q);

        if (sub != 0.0f) {
            float4v Abar = zero4;
#pragma unroll 1
            for (int s = 0; s < 4; s++) {
                float4v a1 = tanh4(u_h);
                float4v A  = a1;
                *(half4v*)(abuf[0] + wslot) = pack4(a1);
                __syncthreads();
                float4v g = gemm4(w21f, abuf[0], c1q);      // a1 M^T + c1
                float4v u;
#pragma unroll
                for (int r = 0; r < 4; r++) u[r] = u_h[r] + hs * g[r];
                float4v a2 = tanh4(u);
#pragma unroll
                for (int r = 0; r < 4; r++) A[r] += 2.0f * a2[r];
                *(half4v*)(abuf[1] + wslot) = pack4(a2);
                __syncthreads();
                g = gemm4(w21f, abuf[1], c1q);
#pragma unroll
                for (int r = 0; r < 4; r++) u[r] = u_h[r] + hs * g[r];
                float4v a3 = tanh4(u);
#pragma unroll
                for (int r = 0; r < 4; r++) A[r] += 2.0f * a3[r];
                *(half4v*)(abuf[0] + wslot) = pack4(a3);
                __syncthreads();
                g = gemm4(w21f, abuf[0], c1q);
#pragma unroll
                for (int r = 0; r < 4; r++) u[r] = u_h[r] + sub * g[r];
                float4v a4 = tanh4(u);
#pragma unroll
                for (int r = 0; r < 4; r++) A[r] += a4[r];
                *(half4v*)(abuf[1] + wslot) = pack4(A);     // |A| <= 6, fp16 ok
                __syncthreads();
                g = gemm4(w21f, abuf[1], zero4);            // A M^T
#pragma unroll
                for (int r = 0; r < 4; r++) {
                    u_h[r]  += s6 * g[r] + sub * c1q[r];
                    Abar[r] += A[r];
                }
            }
            // deferred h update: one W2-GEMM per step
            *(half4v*)(abuf[0] + wslot) = pack4(Abar);      // |Abar| <= 24, fp16 ok
            __syncthreads();
            float4v gw = gemm4(w2f, abuf[0], zero4);
            float fourSub = 4.0f * sub;
#pragma unroll
            for (int r = 0; r < 4; r++) h[r] += s6 * gw[r] + fourSub * b2q[r];
            // publish post-RK h
            *(half4v*)(vbuf + wslot) = pack4(h);
            __syncthreads();
        }
        // (sub==0: vbuf already holds h)

        // ---- gh = h Whh^T + bhh ----
        float4v gh[3];
        {
            const _Float16* p = vbuf + m * 136 + q * 8;
            half8v bf0 = *(const half8v*)(p);
            half8v bf1 = *(const half8v*)(p + 32);
            half8v bf2 = *(const half8v*)(p + 64);
            half8v bf3 = *(const half8v*)(p + 96);
#pragma unroll
            for (int g = 0; g < 3; g++) {
                float4v acc = bhhq[g];
                acc = __builtin_amdgcn_mfma_f32_16x16x32_f16(whhf[g][0], bf0, acc, 0, 0, 0);
                acc = __builtin_amdgcn_mfma_f32_16x16x32_f16(whhf[g][1], bf1, acc, 0, 0, 0);
                acc = __builtin_amdgcn_mfma_f32_16x16x32_f16(whhf[g][2], bf2, acc, 0, 0, 0);
                acc = __builtin_amdgcn_mfma_f32_16x16x32_f16(whhf[g][3], bf3, acc, 0, 0, 0);
                gh[g] = acc;
            }
        }
        __syncthreads();   // all waves done reading vbuf before GRU overwrite

        // ---- GRU (registers) ----
        {
            half4v pk;
#pragma unroll
            for (int r = 0; r < 4; r++) {
                float rr = fast_sig(gi[0][r] + gh[0][r]);
                float zz = fast_sig(gi[1][r] + gh[1][r]);
                float nn = fast_tanh(gi[2][r] + rr * gh[2][r]);
                float hv = (1.0f - zz) * nn + zz * h[r];
                h[r] = hv;
                pk[r] = (_Float16)hv;
            }
            *(half4v*)(vbuf + wslot) = pk;
        }
        // loop-top barrier publishes vbuf
    }

    __syncthreads();

    // ---- epilogue: mu / logvar ----
#pragma unroll
    for (int mat = 0; mat < 2; mat++) {
        const float* Wm = mat ? W_lv : W_mu;
        const float* bm = mat ? b_lv : b_mu;
        float4v acc = *(const float4v*)(bm + 16 * w + q * 4);
        const _Float16* p = vbuf + m * 136 + q * 8;
#pragma unroll
        for (int kt = 0; kt < 4; kt++) {
            half8v af = load_wfrag(Wm, Hn, n0, 32 * kt + q * 8);
            acc = __builtin_amdgcn_mfma_f32_16x16x32_f16(af, *(const half8v*)(p + kt * 32), acc, 0, 0, 0);
        }
        *(float4v*)(out + (size_t)mat * Bn * Hn + (size_t)(blk * 16 + m) * Hn + 16 * w + q * 4) = acc;
    }
}

extern "C" void kernel_launch(void* const* d_in, const int* in_sizes, int n_in,
                              void* d_out, int out_size, void* d_ws, size_t ws_size,
                              hipStream_t stream) {
    (void)in_sizes; (void)n_in; (void)d_ws; (void)ws_size; (void)out_size;
    odernn_kernel<<<dim3(Bn / 16), dim3(512), 0, stream>>>(
        (const float*)d_in[0],  (const float*)d_in[1],  (const float*)d_in[2],
        (const float*)d_in[3],  (const float*)d_in[4],  (const float*)d_in[5],
        (const float*)d_in[6],  (const float*)d_in[7],  (const float*)d_in[8],
        (const float*)d_in[9],  (const float*)d_in[10], (const float*)d_in[11],
        (const float*)d_in[12], (const float*)d_in[13], (float*)d_out);
}